// Round 4
// baseline (95.297 us; speedup 1.0000x reference)
//
#include <hip/hip_runtime.h>

#define IMG_H 2048
#define IMG_W 2048
#define WPR 64       // 32-bit words per row
#define RSTRIPE 8
#define NSTRIPES 256 // covers rows 1..2046
#define MAXBLOCKS 256

typedef unsigned long long ull;

__device__ __forceinline__ unsigned interior_mask(int lane) {
    unsigned m = 0xffffffffu;
    if (lane == 0)  m &= ~1u;
    if (lane == 63) m &= 0x7fffffffu;
    return m;
}

struct RowCtx {
    unsigned b1, b2, b4, b8, b16, lowrun, a_static;
    ull B1, B2, B4, B8, B16, B32;
};

// ps-independent per-row precompute (shared between speculative chains)
__device__ __forceinline__ RowCtx make_ctx(unsigned cs, ull cs_lsb,
                                           unsigned ns, ull ns_lsb, ull ns_msb,
                                           unsigned wk, unsigned interior, int lane) {
    RowCtx c;
    c.b1 = wk & interior;
    unsigned rcs = (cs >> 1) | (((unsigned)((cs_lsb >> 1 >> lane) & 1ull)) << 31);
    unsigned rns = (ns >> 1) | (((unsigned)((ns_lsb >> 1 >> lane) & 1ull)) << 31);
    unsigned lns = (ns << 1) | ((unsigned)(((ns_msb << 1) >> lane) & 1ull));
    c.a_static = cs | (c.b1 & (rcs | lns | ns | rns));
    c.b2  = c.b1 & (c.b1 << 1);
    c.b4  = c.b2 & (c.b2 << 2);
    c.b8  = c.b4 & (c.b4 << 4);
    c.b16 = c.b8 & (c.b8 << 8);
    c.lowrun = c.b1 & (c.b1 ^ (c.b1 + 1u));   // low all-ones run of b1
    c.B1  = __ballot(c.b1 == 0xffffffffu);    // word fully propagates
    c.B2  = c.B1  & (c.B1  << 1);
    c.B4  = c.B2  & (c.B2  << 2);
    c.B8  = c.B4  & (c.B4  << 4);
    c.B16 = c.B8  & (c.B8  << 8);
    c.B32 = c.B16 & (c.B16 << 16);
    return c;
}

// one row of the recurrence: x[j] = a[j] | (b[j] & x[j-1]) closure, bit-parallel
__device__ __forceinline__ unsigned rowstep(unsigned ps, const RowCtx& c, int lane) {
    ull ps_msb = __ballot(ps >> 31);
    ull ps_lsb = __ballot(ps & 1u);
    unsigned lps = (ps << 1) | ((unsigned)(((ps_msb << 1) >> lane) & 1ull));
    unsigned rps = (ps >> 1) | (((unsigned)((ps_lsb >> 1 >> lane) & 1ull)) << 31);
    unsigned x = c.a_static | (c.b1 & (lps | ps | rps));
    x |= c.b1  & (x << 1);
    x |= c.b2  & (x << 2);
    x |= c.b4  & (x << 4);
    x |= c.b8  & (x << 8);
    x |= c.b16 & (x << 16);
    ull X = __ballot(x >> 31);
    X |= c.B1  & (X << 1);
    X |= c.B2  & (X << 2);
    X |= c.B4  & (X << 4);
    X |= c.B8  & (X << 8);
    X |= c.B16 & (X << 16);
    X |= c.B32 & (X << 32);
    unsigned carry = (unsigned)(((X << 1) >> lane) & 1ull);
    x |= carry ? c.lowrun : 0u;
    return x;
}

// ---------------- Phase 1: global max, one atomic per block -----------------
__global__ __launch_bounds__(256) void max_kernel(const float4* __restrict__ in,
                                                  unsigned* __restrict__ maxbits) {
    __shared__ float sm[4];
    const int nvec = IMG_H * IMG_W / 4;           // 1,048,576 float4
    const int chunk = nvec / MAXBLOCKS;           // 4096 per block
    int base = blockIdx.x * chunk + threadIdx.x;
    float m = 0.0f;
#pragma unroll 4
    for (int i = 0; i < chunk / 256; ++i) {       // 16 iters, contiguous
        float4 v = in[base + i * 256];
        m = fmaxf(fmaxf(m, v.x), fmaxf(v.y, fmaxf(v.z, v.w)));
    }
#pragma unroll
    for (int off = 32; off > 0; off >>= 1)
        m = fmaxf(m, __shfl_down(m, off, 64));
    if ((threadIdx.x & 63) == 0) sm[threadIdx.x >> 6] = m;
    __syncthreads();
    if (threadIdx.x == 0) {
        float bm = fmaxf(fmaxf(sm[0], sm[1]), fmaxf(sm[2], sm[3]));
        atomicMax(maxbits, __float_as_uint(bm));  // inputs positive: uint order == float order
    }
}

// ---------------- Phase 2: classify -> bitmasks ----------------
__global__ void binarize_kernel(const float* __restrict__ img,
                                const unsigned* __restrict__ maxbits,
                                ull* __restrict__ S, ull* __restrict__ Wk) {
    int tid = blockIdx.x * blockDim.x + threadIdx.x;
    float maxv = __uint_as_float(*maxbits);
    float high = maxv * 0.15f;
    float low  = high * 0.05f;
    float x = img[tid];
    ull sb = __ballot(x > high);
    ull wb = __ballot((x >= low) && (x <= high));
    if ((threadIdx.x & 63) == 0) {
        S[tid >> 6]  = sb;
        Wk[tid >> 6] = wb;
    }
}

// ---------------- Phase 3: speculative stripes + last-block fix-up ----------
// Each block handles RSTRIPE rows with lower (ps=S[prev]) and upper
// (ps=S[prev]|W[prev]&interior) bounds. Monotonicity => first row where
// bounds agree is exact; all later rows in the stripe are exact. The last
// block to finish (device-scope ticket) sequentially re-runs unconverged
// stripe prefixes in ascending order.
__global__ __launch_bounds__(64) void spec_fix_kernel(const unsigned* __restrict__ S32,
                                                      const unsigned* __restrict__ W32,
                                                      unsigned* __restrict__ N32,
                                                      int* __restrict__ conv,
                                                      unsigned* __restrict__ ticket) {
    const int s = blockIdx.x;
    const int lane = threadIdx.x;
    const int start = 1 + RSTRIPE * s;
    const int end = min(start + RSTRIPE, 2047);  // exclusive
    const unsigned interior = interior_mask(lane);

    // preload whole stripe (independent loads, one latency)
    unsigned pcs = S32[(start - 1) * WPR + lane];
    unsigned pw  = W32[(start - 1) * WPR + lane];
    unsigned csb[RSTRIPE + 1], wkb[RSTRIPE];
#pragma unroll
    for (int u = 0; u <= RSTRIPE; ++u)
        csb[u] = S32[min(start + u, 2047) * WPR + lane];
#pragma unroll
    for (int u = 0; u < RSTRIPE; ++u)
        wkb[u] = W32[min(start + u, 2046) * WPR + lane];

    unsigned psl = pcs;
    unsigned psu = (start == 1) ? pcs : (pcs | (pw & interior));  // row 0 is exact
    unsigned cs = csb[0];
    ull cs_lsb = __ballot(cs & 1u);
    int conv_r = end;           // sentinel: nothing exact in stripe
    bool converged = false;
#pragma unroll
    for (int u = 0; u < RSTRIPE; ++u) {
        const int r = start + u;
        if (r < 2047) {                       // uniform guard
            unsigned ns = csb[u + 1];
            unsigned wk = wkb[u];
            ull ns_lsb = __ballot(ns & 1u);
            ull ns_msb = __ballot(ns >> 31);
            RowCtx c = make_ctx(cs, cs_lsb, ns, ns_lsb, ns_msb, wk, interior, lane);
            unsigned xu = rowstep(psu, c, lane);
            unsigned xl;
            if (!converged) {                 // uniform
                xl = rowstep(psl, c, lane);
                if (__ballot(xl != xu) == 0ull) { converged = true; conv_r = r; }
            } else {
                xl = xu;
            }
            N32[r * WPR + lane] = xu;
            psl = xl;
            psu = xu;
            cs = ns;
            cs_lsb = ns_lsb;
        }
    }
    if (lane == 0) conv[s] = conv_r;

    // ---- release: make this block's N32/conv stores device-visible ----
    __threadfence();                          // all 64 lanes (one wave)
    unsigned t = 0;
    if (lane == 0) t = atomicAdd(ticket, 1u);
    t = __shfl(t, 0, 64);
    if (t != NSTRIPES - 1) return;            // not last block

    // ---- acquire: last block sees everyone's stores ----
    __threadfence();                          // invalidates L1; plain loads now OK

    for (int g = 0; g < NSTRIPES / 64; ++g) {
        int si = g * 64 + lane;
        int start0 = 1 + RSTRIPE * si;
        int cv = conv[si];
        ull bad = __ballot(cv > start0);
        while (bad) {                         // uniform loop, ascending order
            int idx = __ffsll(bad) - 1;
            bad &= bad - 1;
            int bs = g * 64 + idx;
            int bstart = 1 + RSTRIPE * bs;
            int bconv = conv[bs];
            unsigned ps = (bstart == 1) ? S32[lane] : N32[(bstart - 1) * WPR + lane];
            unsigned cs2 = S32[bstart * WPR + lane];
            ull cs2_lsb = __ballot(cs2 & 1u);
            for (int r = bstart; r < bconv; ++r) {
                unsigned ns = S32[(r + 1) * WPR + lane];
                unsigned wk = W32[r * WPR + lane];
                ull ns_lsb = __ballot(ns & 1u);
                ull ns_msb = __ballot(ns >> 31);
                RowCtx c = make_ctx(cs2, cs2_lsb, ns, ns_lsb, ns_msb, wk, interior, lane);
                unsigned x = rowstep(ps, c, lane);
                N32[r * WPR + lane] = x;
                ps = x;
                cs2 = ns;
                cs2_lsb = ns_lsb;
            }
        }
    }
}

// ---------------- Phase 4: materialize fp32 output ----------------
__global__ void expand_kernel(const ull* __restrict__ Ng,
                              const ull* __restrict__ Sg,
                              const ull* __restrict__ Wg,
                              float4* __restrict__ out) {
    int tid = blockIdx.x * blockDim.x + threadIdx.x;
    int p = tid << 2;
    int row = p >> 11;
    int colbase = p & 2047;
    bool edge = (row == 0) || (row == 2047);
    const ull* src = edge ? Sg : Ng;          // edge rows pass through t
    ull sw = src[p >> 6];
    ull ww = Wg[p >> 6];
    int bit = p & 63;
    float4 o;
    float* po = (float*)&o;
#pragma unroll
    for (int k = 0; k < 4; ++k) {
        int b = bit + k;
        bool sn = (sw >> b) & 1ull;
        bool wb = (ww >> b) & 1ull;
        int col = colbase + k;
        bool keep25 = wb && (edge || col == 0 || col == 2047);
        po[k] = sn ? 255.0f : (keep25 ? 25.0f : 0.0f);
    }
    out[tid] = o;
}

extern "C" void kernel_launch(void* const* d_in, const int* in_sizes, int n_in,
                              void* d_out, int out_size, void* d_ws, size_t ws_size,
                              hipStream_t stream) {
    const float* img = (const float*)d_in[0];
    char* ws = (char*)d_ws;
    unsigned* maxbits = (unsigned*)ws;                       // 4 B
    unsigned* ticket  = (unsigned*)(ws + 4);                 // 4 B
    int* conv = (int*)(ws + 64);                             // 1 KiB
    ull* S    = (ull*)(ws + 4096);                           // 512 KiB
    ull* Wk   = (ull*)(ws + 4096 + (1 << 19));               // 512 KiB
    ull* Snew = (ull*)(ws + 4096 + (1 << 20));               // 512 KiB

    hipMemsetAsync(d_ws, 0, 8, stream);   // zero atomicMax cell + ticket

    max_kernel<<<MAXBLOCKS, 256, 0, stream>>>((const float4*)img, maxbits);
    binarize_kernel<<<(IMG_H * IMG_W) / 256, 256, 0, stream>>>(img, maxbits, S, Wk);
    spec_fix_kernel<<<NSTRIPES, 64, 0, stream>>>((const unsigned*)S, (const unsigned*)Wk,
                                                 (unsigned*)Snew, conv, ticket);
    expand_kernel<<<(IMG_H * IMG_W / 4) / 256, 256, 0, stream>>>(Snew, S, Wk, (float4*)d_out);
}

// Round 5
// 82.731 us; speedup vs baseline: 1.1519x; 1.1519x over previous
//
#include <hip/hip_runtime.h>

#define IMG_H 2048
#define IMG_W 2048
#define WPR 64       // 32-bit words per row
#define RSTRIPE 8
#define NSTRIPES 256 // covers rows 1..2046
#define MAXBLOCKS 1024

typedef unsigned long long ull;

__device__ __forceinline__ unsigned interior_mask(int lane) {
    unsigned m = 0xffffffffu;
    if (lane == 0)  m &= ~1u;
    if (lane == 63) m &= 0x7fffffffu;
    return m;
}

struct RowCtx {
    unsigned b1, b2, b4, b8, b16, lowrun, a_static;
    ull B1, B2, B4, B8, B16, B32;
};

// ps-independent per-row precompute (shared between speculative chains)
__device__ __forceinline__ RowCtx make_ctx(unsigned cs, ull cs_lsb,
                                           unsigned ns, ull ns_lsb, ull ns_msb,
                                           unsigned wk, unsigned interior, int lane) {
    RowCtx c;
    c.b1 = wk & interior;
    unsigned rcs = (cs >> 1) | (((unsigned)((cs_lsb >> 1 >> lane) & 1ull)) << 31);
    unsigned rns = (ns >> 1) | (((unsigned)((ns_lsb >> 1 >> lane) & 1ull)) << 31);
    unsigned lns = (ns << 1) | ((unsigned)(((ns_msb << 1) >> lane) & 1ull));
    c.a_static = cs | (c.b1 & (rcs | lns | ns | rns));
    c.b2  = c.b1 & (c.b1 << 1);
    c.b4  = c.b2 & (c.b2 << 2);
    c.b8  = c.b4 & (c.b4 << 4);
    c.b16 = c.b8 & (c.b8 << 8);
    c.lowrun = c.b1 & (c.b1 ^ (c.b1 + 1u));   // low all-ones run of b1
    c.B1  = __ballot(c.b1 == 0xffffffffu);    // word fully propagates
    c.B2  = c.B1  & (c.B1  << 1);
    c.B4  = c.B2  & (c.B2  << 2);
    c.B8  = c.B4  & (c.B4  << 4);
    c.B16 = c.B8  & (c.B8  << 8);
    c.B32 = c.B16 & (c.B16 << 16);
    return c;
}

// one row of the recurrence: x[j] = a[j] | (b[j] & x[j-1]) closure, bit-parallel
__device__ __forceinline__ unsigned rowstep(unsigned ps, const RowCtx& c, int lane) {
    ull ps_msb = __ballot(ps >> 31);
    ull ps_lsb = __ballot(ps & 1u);
    unsigned lps = (ps << 1) | ((unsigned)(((ps_msb << 1) >> lane) & 1ull));
    unsigned rps = (ps >> 1) | (((unsigned)((ps_lsb >> 1 >> lane) & 1ull)) << 31);
    unsigned x = c.a_static | (c.b1 & (lps | ps | rps));
    x |= c.b1  & (x << 1);
    x |= c.b2  & (x << 2);
    x |= c.b4  & (x << 4);
    x |= c.b8  & (x << 8);
    x |= c.b16 & (x << 16);
    ull X = __ballot(x >> 31);
    X |= c.B1  & (X << 1);
    X |= c.B2  & (X << 2);
    X |= c.B4  & (X << 4);
    X |= c.B8  & (X << 8);
    X |= c.B16 & (X << 16);
    X |= c.B32 & (X << 32);
    unsigned carry = (unsigned)(((X << 1) >> lane) & 1ull);
    x |= carry ? c.lowrun : 0u;
    return x;
}

// ---------------- Phase 1: per-block max partials (plain stores) ------------
__global__ __launch_bounds__(256) void max_part_kernel(const float4* __restrict__ in,
                                                       float* __restrict__ partial) {
    __shared__ float sm[4];
    int base = blockIdx.x * 1024 + threadIdx.x;   // 1024 float4 per block
    float m = 0.0f;
#pragma unroll
    for (int i = 0; i < 4; ++i) {
        float4 v = in[base + i * 256];
        m = fmaxf(fmaxf(m, v.x), fmaxf(v.y, fmaxf(v.z, v.w)));
    }
#pragma unroll
    for (int off = 32; off > 0; off >>= 1)
        m = fmaxf(m, __shfl_down(m, off, 64));
    if ((threadIdx.x & 63) == 0) sm[threadIdx.x >> 6] = m;
    __syncthreads();
    if (threadIdx.x == 0)
        partial[blockIdx.x] = fmaxf(fmaxf(sm[0], sm[1]), fmaxf(sm[2], sm[3]));
}

// ---------------- Phase 2: reduce partials in-block, classify -> bitmasks ---
// Each block: 256 threads, 1024 pixels. Lane mapping: wave w, lane l handles
// pixels P+l, P+64+l, P+128+l, P+192+l (P = chunk base) so the 8 ballots are
// exactly the four 64-bit S words and four W words of the chunk.
__global__ __launch_bounds__(256) void binarize_kernel(const float* __restrict__ img,
                                                       const float* __restrict__ partial,
                                                       ull* __restrict__ S,
                                                       ull* __restrict__ Wk) {
    __shared__ float sm[4];
    const int t = threadIdx.x;
    float m = fmaxf(fmaxf(partial[t], partial[t + 256]),
                    fmaxf(partial[t + 512], partial[t + 768]));
#pragma unroll
    for (int off = 32; off > 0; off >>= 1)
        m = fmaxf(m, __shfl_down(m, off, 64));
    if ((t & 63) == 0) sm[t >> 6] = m;
    __syncthreads();
    float maxv = fmaxf(fmaxf(sm[0], sm[1]), fmaxf(sm[2], sm[3]));
    float high = maxv * 0.15f;
    float low  = high * 0.05f;

    const int wave = t >> 6, lane = t & 63;
    const int P = blockIdx.x * 1024 + wave * 256;
    float x0 = img[P + lane];
    float x1 = img[P + 64 + lane];
    float x2 = img[P + 128 + lane];
    float x3 = img[P + 192 + lane];
    ull s0 = __ballot(x0 > high), w0 = __ballot(x0 >= low && x0 <= high);
    ull s1 = __ballot(x1 > high), w1 = __ballot(x1 >= low && x1 <= high);
    ull s2 = __ballot(x2 > high), w2 = __ballot(x2 >= low && x2 <= high);
    ull s3 = __ballot(x3 > high), w3 = __ballot(x3 >= low && x3 <= high);
    const int wb = P >> 6;   // word index base
    ull vS = lane == 0 ? s0 : lane == 1 ? s1 : lane == 2 ? s2 : s3;
    ull vW = lane == 4 ? w0 : lane == 5 ? w1 : lane == 6 ? w2 : w3;
    if (lane < 4)      S[wb + lane] = vS;
    else if (lane < 8) Wk[wb + lane - 4] = vW;
}

// ---------------- Phase 3a: parallel speculative stripes ----------------
__global__ __launch_bounds__(64) void spec_kernel(const unsigned* __restrict__ S32,
                                                  const unsigned* __restrict__ W32,
                                                  unsigned* __restrict__ N32,
                                                  int* __restrict__ conv) {
    const int s = blockIdx.x;
    const int lane = threadIdx.x;
    const int start = 1 + RSTRIPE * s;
    const int end = min(start + RSTRIPE, 2047);  // exclusive
    const unsigned interior = interior_mask(lane);

    unsigned pcs = S32[(start - 1) * WPR + lane];
    unsigned pw  = W32[(start - 1) * WPR + lane];
    unsigned csb[RSTRIPE + 1], wkb[RSTRIPE];
#pragma unroll
    for (int u = 0; u <= RSTRIPE; ++u)
        csb[u] = S32[min(start + u, 2047) * WPR + lane];
#pragma unroll
    for (int u = 0; u < RSTRIPE; ++u)
        wkb[u] = W32[min(start + u, 2046) * WPR + lane];

    unsigned psl = pcs;
    unsigned psu = (start == 1) ? pcs : (pcs | (pw & interior));  // row 0 is exact
    unsigned cs = csb[0];
    ull cs_lsb = __ballot(cs & 1u);
    int conv_r = end;           // sentinel: nothing exact in stripe
    bool converged = false;
#pragma unroll
    for (int u = 0; u < RSTRIPE; ++u) {
        const int r = start + u;
        if (r < 2047) {                       // uniform guard
            unsigned ns = csb[u + 1];
            unsigned wk = wkb[u];
            ull ns_lsb = __ballot(ns & 1u);
            ull ns_msb = __ballot(ns >> 31);
            RowCtx c = make_ctx(cs, cs_lsb, ns, ns_lsb, ns_msb, wk, interior, lane);
            unsigned xu = rowstep(psu, c, lane);
            unsigned xl;
            if (!converged) {                 // uniform
                xl = rowstep(psl, c, lane);
                if (__ballot(xl != xu) == 0ull) { converged = true; conv_r = r; }
            } else {
                xl = xu;
            }
            N32[r * WPR + lane] = xu;
            psl = xl;
            psu = xu;
            cs = ns;
            cs_lsb = ns_lsb;
        }
    }
    if (lane == 0) conv[s] = conv_r;
}

// ---------------- Phase 3b: sequential fix-up of unconverged prefixes -------
__global__ __launch_bounds__(64) void fix_kernel(const unsigned* __restrict__ S32,
                                                 const unsigned* __restrict__ W32,
                                                 unsigned* N32,
                                                 const int* __restrict__ conv) {
    const int lane = threadIdx.x;
    const unsigned interior = interior_mask(lane);
    for (int g = 0; g < NSTRIPES / 64; ++g) {
        int s = g * 64 + lane;
        int start0 = 1 + RSTRIPE * s;
        int cv = conv[s];
        ull bad = __ballot(cv > start0);
        while (bad) {                         // uniform loop, ascending order
            int idx = __ffsll(bad) - 1;
            bad &= bad - 1;
            int bs = g * 64 + idx;
            int bstart = 1 + RSTRIPE * bs;
            int bconv = conv[bs];
            unsigned ps = (bstart == 1) ? S32[lane] : N32[(bstart - 1) * WPR + lane];
            unsigned cs = S32[bstart * WPR + lane];
            ull cs_lsb = __ballot(cs & 1u);
            for (int r = bstart; r < bconv; ++r) {
                unsigned ns = S32[(r + 1) * WPR + lane];
                unsigned wk = W32[r * WPR + lane];
                ull ns_lsb = __ballot(ns & 1u);
                ull ns_msb = __ballot(ns >> 31);
                RowCtx c = make_ctx(cs, cs_lsb, ns, ns_lsb, ns_msb, wk, interior, lane);
                unsigned x = rowstep(ps, c, lane);
                N32[r * WPR + lane] = x;
                ps = x;
                cs = ns;
                cs_lsb = ns_lsb;
            }
        }
    }
}

// ---------------- Phase 4: materialize fp32 output ----------------
__global__ void expand_kernel(const ull* __restrict__ Ng,
                              const ull* __restrict__ Sg,
                              const ull* __restrict__ Wg,
                              float4* __restrict__ out) {
    int tid = blockIdx.x * blockDim.x + threadIdx.x;
    int p = tid << 2;
    int row = p >> 11;
    int colbase = p & 2047;
    bool edge = (row == 0) || (row == 2047);
    const ull* src = edge ? Sg : Ng;          // edge rows pass through t
    ull sw = src[p >> 6];
    ull ww = Wg[p >> 6];
    int bit = p & 63;
    float4 o;
    float* po = (float*)&o;
#pragma unroll
    for (int k = 0; k < 4; ++k) {
        int b = bit + k;
        bool sn = (sw >> b) & 1ull;
        bool wb = (ww >> b) & 1ull;
        int col = colbase + k;
        bool keep25 = wb && (edge || col == 0 || col == 2047);
        po[k] = sn ? 255.0f : (keep25 ? 25.0f : 0.0f);
    }
    out[tid] = o;
}

extern "C" void kernel_launch(void* const* d_in, const int* in_sizes, int n_in,
                              void* d_out, int out_size, void* d_ws, size_t ws_size,
                              hipStream_t stream) {
    const float* img = (const float*)d_in[0];
    char* ws = (char*)d_ws;
    int* conv = (int*)(ws + 64);                             // 1 KiB
    float* partial = (float*)(ws + 2048);                    // 4 KiB (1024 floats)
    ull* S    = (ull*)(ws + 8192);                           // 512 KiB
    ull* Wk   = (ull*)(ws + 8192 + (1 << 19));               // 512 KiB
    ull* Snew = (ull*)(ws + 8192 + (1 << 20));               // 512 KiB

    max_part_kernel<<<MAXBLOCKS, 256, 0, stream>>>((const float4*)img, partial);
    binarize_kernel<<<(IMG_H * IMG_W) / 1024, 256, 0, stream>>>(img, partial, S, Wk);
    spec_kernel<<<NSTRIPES, 64, 0, stream>>>((const unsigned*)S, (const unsigned*)Wk,
                                             (unsigned*)Snew, conv);
    fix_kernel<<<1, 64, 0, stream>>>((const unsigned*)S, (const unsigned*)Wk,
                                     (unsigned*)Snew, conv);
    expand_kernel<<<(IMG_H * IMG_W / 4) / 256, 256, 0, stream>>>(Snew, S, Wk, (float4*)d_out);
}